// Round 16
// baseline (51.556 us; speedup 1.0000x reference)
//
#include <hip/hip_runtime.h>

#define B_N    1024
#define F_DIMC 768
#define M_DIM  512
#define C_N    100
#define KSTEP  32
#define NSTEP  (F_DIMC / KSTEP)   // 24 k-steps
#define NGEMM  512                // 32 row-tiles x 16 col-tiles (32x32 out)
#define NIDX   25                 // 25 blocks x 4 waves = 100 classes

typedef float f32x4 __attribute__((ext_vector_type(4)));
typedef short s16x8 __attribute__((ext_vector_type(8)));

__device__ __forceinline__ unsigned int f2bf(float x) {
  unsigned int u = __builtin_bit_cast(unsigned int, x);
  return (u + 0x7fffu + ((u >> 16) & 1u)) >> 16;
}
__device__ __forceinline__ float bf2f(unsigned int h) {
  return __builtin_bit_cast(float, h << 16);
}

// ---------------------------------------------------------------------------
// Kernel 1 (R15 verbatim): MFMA gemm feat = relu(X@W) (split-bf16, 3-term)
// + ballot-rank index build.
// ---------------------------------------------------------------------------
__global__ __launch_bounds__(256) void gemm_index_kernel(
    const float* __restrict__ X, const float* __restrict__ W,
    const int* __restrict__ labels, float* __restrict__ feat,
    int* __restrict__ counts, int* __restrict__ idx) {
  __shared__ unsigned short Ah[2][32][40], Al[2][32][40];  // [row][k] 80B pitch
  __shared__ unsigned short Bh[2][32][40], Bl[2][32][40];  // [col][k] 80B pitch
  __shared__ int lab[B_N];

  const int t = threadIdx.x;
  const int b = (int)blockIdx.x;

  if (b >= NGEMM) {  // ---- index path ----
    for (int i = t; i < B_N; i += 256) lab[i] = labels[i];
    __syncthreads();
    const int w    = t >> 6;
    const int lane = t & 63;
    const int c    = (b - NGEMM) * 4 + w;
    if (c < C_N) {
      int base = 0;
      for (int ch = 0; ch < 16; ++ch) {
        const int j = ch * 64 + lane;
        const bool hit = (lab[j] == c);
        const unsigned long long mask = __ballot(hit);
        if (hit) {
          const int r = __popcll(mask & ((1ull << lane) - 1ull));
          idx[c * B_N + base + r] = j;
        }
        base += __popcll(mask);
      }
      if (lane == 0) counts[c] = base;
    }
    return;
  }

  // ---- MFMA gemm path ----
  const int bm = (b >> 4) * 32;
  const int bn = (b & 15) * 32;

  const bool isX = (t < 128);
  const int xr = t >> 2;
  const int xk = (t & 3) * 8;
  const int uu = isX ? 0 : (t - 128);
  const int wk = (uu >> 3) * 2;
  const int wc = (uu & 7) * 4;

  const float* __restrict__ Xp = X + (size_t)(bm + xr) * F_DIMC + xk;
  const float* __restrict__ Wp = W + (size_t)wk * M_DIM + bn + wc;

  const int lane = t & 63;
  const int wv   = t >> 6;
  const int m0 = (wv & 1) * 16;
  const int n0 = (wv >> 1) * 16;
  const int fr = lane & 15;
  const int fq = (lane >> 4) * 8;

  f32x4 acc = {0.f, 0.f, 0.f, 0.f};

  float4 ra0, ra1, rb0, rb1;
  if (isX) {
    ra0 = *(const float4*)(Xp);
    ra1 = *(const float4*)(Xp + 4);
  } else {
    rb0 = *(const float4*)(Wp);
    rb1 = *(const float4*)(Wp + M_DIM);
  }

  auto STAGE = [&](int buf) {
    if (isX) {
      const float v[8] = {ra0.x, ra0.y, ra0.z, ra0.w,
                          ra1.x, ra1.y, ra1.z, ra1.w};
      s16x8 hv, lv;
#pragma unroll
      for (int j = 0; j < 8; ++j) {
        const unsigned int hb = f2bf(v[j]);
        hv[j] = (short)hb;
        lv[j] = (short)f2bf(v[j] - bf2f(hb));
      }
      *(s16x8*)&Ah[buf][xr][xk] = hv;
      *(s16x8*)&Al[buf][xr][xk] = lv;
    } else {
      const float a[4] = {rb0.x, rb0.y, rb0.z, rb0.w};
      const float d[4] = {rb1.x, rb1.y, rb1.z, rb1.w};
#pragma unroll
      for (int i = 0; i < 4; ++i) {
        const unsigned int ha = f2bf(a[i]), hd = f2bf(d[i]);
        const unsigned int la = f2bf(a[i] - bf2f(ha));
        const unsigned int ld = f2bf(d[i] - bf2f(hd));
        *(unsigned int*)&Bh[buf][wc + i][wk] = ha | (hd << 16);
        *(unsigned int*)&Bl[buf][wc + i][wk] = la | (ld << 16);
      }
    }
  };

  STAGE(0);
  __syncthreads();

  for (int it = 0; it < NSTEP; ++it) {
    const int cur = it & 1;
    if (it + 1 < NSTEP) {
      const int k0 = (it + 1) * KSTEP;
      if (isX) {
        ra0 = *(const float4*)(Xp + k0);
        ra1 = *(const float4*)(Xp + k0 + 4);
      } else {
        rb0 = *(const float4*)(Wp + (size_t)k0 * M_DIM);
        rb1 = *(const float4*)(Wp + (size_t)(k0 + 1) * M_DIM);
      }
    }
    const s16x8 ah = *(const s16x8*)&Ah[cur][m0 + fr][fq];
    const s16x8 al = *(const s16x8*)&Al[cur][m0 + fr][fq];
    const s16x8 bh = *(const s16x8*)&Bh[cur][n0 + fr][fq];
    const s16x8 bl = *(const s16x8*)&Bl[cur][n0 + fr][fq];
    acc = __builtin_amdgcn_mfma_f32_16x16x32_bf16(ah, bh, acc, 0, 0, 0);
    acc = __builtin_amdgcn_mfma_f32_16x16x32_bf16(al, bh, acc, 0, 0, 0);
    acc = __builtin_amdgcn_mfma_f32_16x16x32_bf16(ah, bl, acc, 0, 0, 0);
    if (it + 1 < NSTEP) STAGE(cur ^ 1);
    __syncthreads();
  }

  const int r0 = (lane >> 4) * 4;
#pragma unroll
  for (int r = 0; r < 4; ++r)
    feat[(size_t)(bm + m0 + r0 + r) * M_DIM + bn + n0 + fr] =
        fmaxf(acc[r], 0.0f);
}

// ---------------------------------------------------------------------------
// Kernel 2: phi 16-row panels + mu/count, LPT class order.
// grid = (33, rank): x<32 -> 16 rows x 512 cols of phi[class(rank)];
// x==32 -> mu/count. Each block resolves rank -> class by stable selection
// over counts (computed in-block; deterministic).
// acc[4][8]; chunk=16 LDS stage; nt float4 stores (32 KB burst per block).
// ---------------------------------------------------------------------------
__global__ __launch_bounds__(256) void phi_mu_kernel(
    const float* __restrict__ feat, const int* __restrict__ counts,
    const int* __restrict__ idx, float* __restrict__ phi,
    float* __restrict__ mu, float* __restrict__ cnt_out) {
  __shared__ float F[16][M_DIM];
  __shared__ int   cls_sh;
  const int t = threadIdx.x;

  // ---- rank -> class (LPT: descending count, stable by class id) ----
  {
    __shared__ int cnt_sh[C_N];
    for (int i = t; i < C_N; i += 256) cnt_sh[i] = counts[i];
    __syncthreads();
    const int rank = (int)blockIdx.y;
    if (t < C_N) {
      const int my = cnt_sh[t];
      int r = 0;
      for (int j = 0; j < C_N; ++j) {
        const int cj = cnt_sh[j];
        r += (cj > my) || (cj == my && j < t);
      }
      if (r == rank) cls_sh = t;
    }
    __syncthreads();
  }
  const int c = cls_sh;
  const int n = counts[c];
  const int* __restrict__ id = idx + c * B_N;

  if (blockIdx.x == 32) {  // ---- mu / count path ----
    float2 acc = make_float2(0.f, 0.f);
    for (int s = 0; s < n; ++s) {
      const float2 q = *(const float2*)&feat[(size_t)id[s] * M_DIM + t * 2];
      acc.x += q.x;
      acc.y += q.y;
    }
    *(float2*)&mu[(size_t)c * M_DIM + t * 2] = acc;
    if (t == 0) cnt_out[c] = (float)n;
    return;
  }

  // ---- phi panel: rows 16*px..+16, all 512 cols ----
  const int px = (int)blockIdx.x;      // 0..31
  const int tr = t >> 6;               // row group 0..3 (x4 rows)
  const int tc = t & 63;               // cols tc*4 and 256+tc*4

  float acc[4][8] = {};  // [r][q]: q<4 -> col tc*4+q ; q>=4 -> 256+tc*4+q-4

  for (int s0 = 0; s0 < n; s0 += 16) {
    const int chunk  = min(16, n - s0);
    if (s0) __syncthreads();           // protect F before overwrite
    const int nslots = chunk << 7;     // chunk * 128 float4 per row
    for (int v = t; v < nslots; v += 256) {
      const int sl = v >> 7;
      const int fp = (v & 127) << 2;
      *(float4*)&F[sl][fp] =
          *(const float4*)&feat[(size_t)id[s0 + sl] * M_DIM + fp];
    }
    __syncthreads();
    for (int sl = 0; sl < chunk; ++sl) {
      const float4 a0 = *(const float4*)&F[sl][px * 16 + tr * 4];  // bcast
      const float4 b0 = *(const float4*)&F[sl][tc * 4];            // contig
      const float4 b1 = *(const float4*)&F[sl][256 + tc * 4];      // contig
      const float av[4] = {a0.x, a0.y, a0.z, a0.w};
      const float bv[8] = {b0.x, b0.y, b0.z, b0.w, b1.x, b1.y, b1.z, b1.w};
#pragma unroll
      for (int r = 0; r < 4; ++r)
#pragma unroll
        for (int q = 0; q < 8; ++q)
          acc[r][q] += av[r] * bv[q];
    }
  }

  float* __restrict__ out = phi + (size_t)c * M_DIM * M_DIM;
#pragma unroll
  for (int r = 0; r < 4; ++r) {
    const size_t row = (size_t)(px * 16 + tr * 4 + r) * M_DIM;
    const f32x4 o0 = {acc[r][0], acc[r][1], acc[r][2], acc[r][3]};
    const f32x4 o1 = {acc[r][4], acc[r][5], acc[r][6], acc[r][7]};
    __builtin_nontemporal_store(o0, (f32x4*)&out[row + tc * 4]);
    __builtin_nontemporal_store(o1, (f32x4*)&out[row + 256 + tc * 4]);
  }
}

// ---------------------------------------------------------------------------
extern "C" void kernel_launch(void* const* d_in, const int* in_sizes, int n_in,
                              void* d_out, int out_size, void* d_ws,
                              size_t ws_size, hipStream_t stream) {
  const float* X      = (const float*)d_in[0];
  const float* W      = (const float*)d_in[1];
  const int*   labels = (const int*)d_in[2];

  float* out = (float*)d_out;
  float* phi = out;                                // C*M*M
  float* mu  = out + (size_t)C_N * M_DIM * M_DIM;  // C*M
  float* cnt = mu + (size_t)C_N * M_DIM;           // C

  float* feat   = (float*)d_ws;                    // B*M fp32 = 2 MB
  int*   counts = (int*)((char*)d_ws + (size_t)B_N * M_DIM * sizeof(float));
  int*   idx    = counts + 128;                    // C*B ints

  hipLaunchKernelGGL(gemm_index_kernel, dim3(NGEMM + NIDX), dim3(256), 0,
                     stream, X, W, labels, feat, counts, idx);
  hipLaunchKernelGGL(phi_mu_kernel, dim3(33, C_N), dim3(256), 0, stream,
                     feat, counts, idx, phi, mu, cnt);
}

// Round 17
// 50.310 us; speedup vs baseline: 1.0248x; 1.0248x over previous
//
#include <hip/hip_runtime.h>

#define B_N    1024
#define F_DIMC 768
#define M_DIM  512
#define C_N    100
#define KSTEP  32
#define NSTEP  (F_DIMC / KSTEP)   // 24 k-steps
#define NGEMM  512                // 32 row-tiles x 16 col-tiles (32x32 out)
#define NIDX   25                 // 25 blocks x 4 waves = 100 classes
#define NUNITS (17 * C_N)         // 1700 phi/mu units
#define PBLK   850                // persistent phi blocks (exactly 2 units each)

typedef float f32x4 __attribute__((ext_vector_type(4)));
typedef short s16x8 __attribute__((ext_vector_type(8)));

__device__ __forceinline__ unsigned int f2bf(float x) {
  unsigned int u = __builtin_bit_cast(unsigned int, x);
  return (u + 0x7fffu + ((u >> 16) & 1u)) >> 16;
}
__device__ __forceinline__ float bf2f(unsigned int h) {
  return __builtin_bit_cast(float, h << 16);
}

// ---------------------------------------------------------------------------
// Kernel 1 (R15 verbatim): MFMA gemm feat = relu(X@W) (split-bf16, 3-term)
// + ballot-rank index build.
// ---------------------------------------------------------------------------
__global__ __launch_bounds__(256) void gemm_index_kernel(
    const float* __restrict__ X, const float* __restrict__ W,
    const int* __restrict__ labels, float* __restrict__ feat,
    int* __restrict__ counts, int* __restrict__ idx) {
  __shared__ unsigned short Ah[2][32][40], Al[2][32][40];  // [row][k] 80B pitch
  __shared__ unsigned short Bh[2][32][40], Bl[2][32][40];  // [col][k] 80B pitch
  __shared__ int lab[B_N];

  const int t = threadIdx.x;
  const int b = (int)blockIdx.x;

  if (b >= NGEMM) {  // ---- index path ----
    for (int i = t; i < B_N; i += 256) lab[i] = labels[i];
    __syncthreads();
    const int w    = t >> 6;
    const int lane = t & 63;
    const int c    = (b - NGEMM) * 4 + w;
    if (c < C_N) {
      int base = 0;
      for (int ch = 0; ch < 16; ++ch) {
        const int j = ch * 64 + lane;
        const bool hit = (lab[j] == c);
        const unsigned long long mask = __ballot(hit);
        if (hit) {
          const int r = __popcll(mask & ((1ull << lane) - 1ull));
          idx[c * B_N + base + r] = j;
        }
        base += __popcll(mask);
      }
      if (lane == 0) counts[c] = base;
    }
    return;
  }

  // ---- MFMA gemm path ----
  const int bm = (b >> 4) * 32;
  const int bn = (b & 15) * 32;

  const bool isX = (t < 128);
  const int xr = t >> 2;
  const int xk = (t & 3) * 8;
  const int uu = isX ? 0 : (t - 128);
  const int wk = (uu >> 3) * 2;
  const int wc = (uu & 7) * 4;

  const float* __restrict__ Xp = X + (size_t)(bm + xr) * F_DIMC + xk;
  const float* __restrict__ Wp = W + (size_t)wk * M_DIM + bn + wc;

  const int lane = t & 63;
  const int wv   = t >> 6;
  const int m0 = (wv & 1) * 16;
  const int n0 = (wv >> 1) * 16;
  const int fr = lane & 15;
  const int fq = (lane >> 4) * 8;

  f32x4 acc = {0.f, 0.f, 0.f, 0.f};

  float4 ra0, ra1, rb0, rb1;
  if (isX) {
    ra0 = *(const float4*)(Xp);
    ra1 = *(const float4*)(Xp + 4);
  } else {
    rb0 = *(const float4*)(Wp);
    rb1 = *(const float4*)(Wp + M_DIM);
  }

  auto STAGE = [&](int buf) {
    if (isX) {
      const float v[8] = {ra0.x, ra0.y, ra0.z, ra0.w,
                          ra1.x, ra1.y, ra1.z, ra1.w};
      s16x8 hv, lv;
#pragma unroll
      for (int j = 0; j < 8; ++j) {
        const unsigned int hb = f2bf(v[j]);
        hv[j] = (short)hb;
        lv[j] = (short)f2bf(v[j] - bf2f(hb));
      }
      *(s16x8*)&Ah[buf][xr][xk] = hv;
      *(s16x8*)&Al[buf][xr][xk] = lv;
    } else {
      const float a[4] = {rb0.x, rb0.y, rb0.z, rb0.w};
      const float d[4] = {rb1.x, rb1.y, rb1.z, rb1.w};
#pragma unroll
      for (int i = 0; i < 4; ++i) {
        const unsigned int ha = f2bf(a[i]), hd = f2bf(d[i]);
        const unsigned int la = f2bf(a[i] - bf2f(ha));
        const unsigned int ld = f2bf(d[i] - bf2f(hd));
        *(unsigned int*)&Bh[buf][wc + i][wk] = ha | (hd << 16);
        *(unsigned int*)&Bl[buf][wc + i][wk] = la | (ld << 16);
      }
    }
  };

  STAGE(0);
  __syncthreads();

  for (int it = 0; it < NSTEP; ++it) {
    const int cur = it & 1;
    if (it + 1 < NSTEP) {
      const int k0 = (it + 1) * KSTEP;
      if (isX) {
        ra0 = *(const float4*)(Xp + k0);
        ra1 = *(const float4*)(Xp + k0 + 4);
      } else {
        rb0 = *(const float4*)(Wp + (size_t)k0 * M_DIM);
        rb1 = *(const float4*)(Wp + (size_t)(k0 + 1) * M_DIM);
      }
    }
    const s16x8 ah = *(const s16x8*)&Ah[cur][m0 + fr][fq];
    const s16x8 al = *(const s16x8*)&Al[cur][m0 + fr][fq];
    const s16x8 bh = *(const s16x8*)&Bh[cur][n0 + fr][fq];
    const s16x8 bl = *(const s16x8*)&Bl[cur][n0 + fr][fq];
    acc = __builtin_amdgcn_mfma_f32_16x16x32_bf16(ah, bh, acc, 0, 0, 0);
    acc = __builtin_amdgcn_mfma_f32_16x16x32_bf16(al, bh, acc, 0, 0, 0);
    acc = __builtin_amdgcn_mfma_f32_16x16x32_bf16(ah, bl, acc, 0, 0, 0);
    if (it + 1 < NSTEP) STAGE(cur ^ 1);
    __syncthreads();
  }

  const int r0 = (lane >> 4) * 4;
#pragma unroll
  for (int r = 0; r < 4; ++r)
    feat[(size_t)(bm + m0 + r0 + r) * M_DIM + bn + n0 + fr] =
        fmaxf(acc[r], 0.0f);
}

// ---------------------------------------------------------------------------
// Kernel 2: persistent phi/mu with store/stage overlap.
// 850 blocks x 2 units each. Unit u: c=u/17, sub=u%17; sub<16 -> 32-row x
// 512-col phi panel (R15 inner structure verbatim); sub==16 -> mu/count.
// Next unit's first-chunk global loads are issued BEFORE this unit's nt
// stores, so the (counted) vmcnt wait for those loads does not drain the
// stores -> next stage/compute overlaps store drain.
// ---------------------------------------------------------------------------
__global__ __launch_bounds__(256) void phi_mu_kernel(
    const float* __restrict__ feat, const int* __restrict__ counts,
    const int* __restrict__ idx, float* __restrict__ phi,
    float* __restrict__ mu, float* __restrict__ cnt_out) {
  __shared__ float F[16][M_DIM];
  const int t = threadIdx.x;
  const int b = (int)blockIdx.x;

  float4 pf[8];

  auto PREFETCH = [&](int u) {  // first-chunk loads -> regs
    if (u >= NUNITS) return;
    const int c = u / 17, sub = u % 17;
    if (sub == 16) return;
    const int n = counts[c];
    const int chunk = n < 16 ? n : 16;
    const int* __restrict__ id = idx + c * B_N;
#pragma unroll
    for (int i = 0; i < 8; ++i) {
      const int v  = t + (i << 8);
      const int sl = v >> 7;
      if (sl < chunk) {
        const int fp = (v & 127) << 2;
        pf[i] = *(const float4*)&feat[(size_t)id[sl] * M_DIM + fp];
      }
    }
  };

  PREFETCH(b);

  for (int u = b; u < NUNITS; u += PBLK) {
    const int c   = u / 17;
    const int sub = u - c * 17;
    const int n = counts[c];
    const int* __restrict__ id = idx + c * B_N;

    if (sub == 16) {  // ---- mu / count (direct global reads) ----
      float2 acc = make_float2(0.f, 0.f);
      for (int s = 0; s < n; ++s) {
        const float2 q = *(const float2*)&feat[(size_t)id[s] * M_DIM + t * 2];
        acc.x += q.x;
        acc.y += q.y;
      }
      PREFETCH(u + PBLK);
      *(float2*)&mu[(size_t)c * M_DIM + t * 2] = acc;
      if (t == 0) cnt_out[c] = (float)n;
      continue;
    }

    // ---- phi panel: rows 32*sub..+32, all 512 cols ----
    const int px = sub;
    const int tr = t >> 6;
    const int tc = t & 63;

    float acc[8][8] = {};

    // chunk 0 from prefetched regs
    {
      const int chunk = n < 16 ? n : 16;
#pragma unroll
      for (int i = 0; i < 8; ++i) {
        const int v  = t + (i << 8);
        const int sl = v >> 7;
        if (sl < chunk) *(float4*)&F[sl][(v & 127) << 2] = pf[i];
      }
      __syncthreads();
      for (int sl = 0; sl < chunk; ++sl) {
        const float4 a0 = *(const float4*)&F[sl][px * 32 + tr * 8];
        const float4 a1 = *(const float4*)&F[sl][px * 32 + tr * 8 + 4];
        const float4 b0 = *(const float4*)&F[sl][tc * 4];
        const float4 b1 = *(const float4*)&F[sl][256 + tc * 4];
        const float av[8] = {a0.x, a0.y, a0.z, a0.w, a1.x, a1.y, a1.z, a1.w};
        const float bv[8] = {b0.x, b0.y, b0.z, b0.w, b1.x, b1.y, b1.z, b1.w};
#pragma unroll
        for (int r = 0; r < 8; ++r)
#pragma unroll
          for (int q = 0; q < 8; ++q)
            acc[r][q] += av[r] * bv[q];
      }
    }

    // remaining chunks: stage direct from global
    for (int s0 = 16; s0 < n; s0 += 16) {
      const int chunk = min(16, n - s0);
      __syncthreads();
      const int nslots = chunk << 7;
      for (int v = t; v < nslots; v += 256) {
        const int sl = v >> 7;
        const int fp = (v & 127) << 2;
        *(float4*)&F[sl][fp] =
            *(const float4*)&feat[(size_t)id[s0 + sl] * M_DIM + fp];
      }
      __syncthreads();
      for (int sl = 0; sl < chunk; ++sl) {
        const float4 a0 = *(const float4*)&F[sl][px * 32 + tr * 8];
        const float4 a1 = *(const float4*)&F[sl][px * 32 + tr * 8 + 4];
        const float4 b0 = *(const float4*)&F[sl][tc * 4];
        const float4 b1 = *(const float4*)&F[sl][256 + tc * 4];
        const float av[8] = {a0.x, a0.y, a0.z, a0.w, a1.x, a1.y, a1.z, a1.w};
        const float bv[8] = {b0.x, b0.y, b0.z, b0.w, b1.x, b1.y, b1.z, b1.w};
#pragma unroll
        for (int r = 0; r < 8; ++r)
#pragma unroll
          for (int q = 0; q < 8; ++q)
            acc[r][q] += av[r] * bv[q];
      }
    }

    PREFETCH(u + PBLK);  // issue next unit's loads BEFORE stores

    float* __restrict__ out = phi + (size_t)c * M_DIM * M_DIM;
#pragma unroll
    for (int r = 0; r < 8; ++r) {
      const size_t row = (size_t)(px * 32 + tr * 8 + r) * M_DIM;
      const f32x4 o0 = {acc[r][0], acc[r][1], acc[r][2], acc[r][3]};
      const f32x4 o1 = {acc[r][4], acc[r][5], acc[r][6], acc[r][7]};
      __builtin_nontemporal_store(o0, (f32x4*)&out[row + tc * 4]);
      __builtin_nontemporal_store(o1, (f32x4*)&out[row + 256 + tc * 4]);
    }
    __syncthreads();  // protect F before next unit's ds_write
  }
}

// ---------------------------------------------------------------------------
extern "C" void kernel_launch(void* const* d_in, const int* in_sizes, int n_in,
                              void* d_out, int out_size, void* d_ws,
                              size_t ws_size, hipStream_t stream) {
  const float* X      = (const float*)d_in[0];
  const float* W      = (const float*)d_in[1];
  const int*   labels = (const int*)d_in[2];

  float* out = (float*)d_out;
  float* phi = out;                                // C*M*M
  float* mu  = out + (size_t)C_N * M_DIM * M_DIM;  // C*M
  float* cnt = mu + (size_t)C_N * M_DIM;           // C

  float* feat   = (float*)d_ws;                    // B*M fp32 = 2 MB
  int*   counts = (int*)((char*)d_ws + (size_t)B_N * M_DIM * sizeof(float));
  int*   idx    = counts + 128;                    // C*B ints

  hipLaunchKernelGGL(gemm_index_kernel, dim3(NGEMM + NIDX), dim3(256), 0,
                     stream, X, W, labels, feat, counts, idx);
  hipLaunchKernelGGL(phi_mu_kernel, dim3(PBLK), dim3(256), 0, stream,
                     feat, counts, idx, phi, mu, cnt);
}